// Round 1
// baseline (881.563 us; speedup 1.0000x reference)
//
#include <hip/hip_runtime.h>
#include <stdint.h>

#define BATCH   512
#define NFEAT   128
#define EWORDS  64     // E = 2048 bits -> 64 uint32 words
#define HSIZE   8192
#define HWORDS  256    // 8192 bits -> 256 uint32 words
#define NCLS    10
#define THRESH_I 4

// ---------------------------------------------------------------------------
// Encode: thermometer bits of x into bit matrix act0[word][batch].
// Word w holds features 2w (bits 0..15) and 2w+1 (bits 16..31).
// Also zeroes the outAcc accumulator (harness poisons ws with 0xAA).
// ---------------------------------------------------------------------------
__global__ __launch_bounds__(256) void encode_kernel(
    const float* __restrict__ x,
    uint32_t* __restrict__ act0,
    float* __restrict__ outAcc) {
  int t = blockIdx.x * 256 + threadIdx.x;        // 32768 threads
  if (t < BATCH * NCLS) outAcc[t] = 0.0f;
  int b = t >> 6;          // batch
  int w = t & 63;          // word index
  if (b < BATCH) {
    float u0 = x[b * NFEAT + 2 * w] * 16.0f;
    float u1 = x[b * NFEAT + 2 * w + 1] * 16.0f;
    uint32_t word = 0;
#pragma unroll
    for (int j = 0; j < 16; ++j) {
      word |= (u0 > (float)j ? 1u : 0u) << j;
      word |= (u1 > (float)j ? 1u : 0u) << (16 + j);
    }
    act0[w * BATCH + b] = word;
  }
}

// ---------------------------------------------------------------------------
// Layer: stream W rows (dense f32, values in {-1,0,+1}); per nonzero element
// (found via ballot, wave-uniform scalar loop), update z accumulators for all
// 512 batches (8 per lane). Threshold z>=4 -> output bit matrix.
// Block = 512 threads (8 waves), 32 rows per block (one output word index).
// ---------------------------------------------------------------------------
template <int P>
__device__ __forceinline__ void proc_comp(float v, int e_base_plus_j,
                                          const uint32_t* __restrict__ actIn,
                                          int lane, int* z) {
  uint64_t m  = __ballot(v != 0.0f);
  if (m == 0ull) return;
  uint64_t pm = __ballot(v > 0.0f);
  while (m) {
    uint32_t src = (uint32_t)__builtin_ctzll(m);
    m &= m - 1;
    int e = e_base_plus_j + 4 * (int)src;        // element index (wave-uniform)
    int s = ((pm >> src) & 1ull) ? 1 : -1;
    const uint32_t* aw = actIn + (size_t)(e >> 5) * BATCH + lane;
    uint32_t sh = (uint32_t)(e & 31);
#pragma unroll
    for (int i = 0; i < 8; ++i) {
      int bit = (int)((aw[i * 64] >> sh) & 1u);
      z[i] += s * bit;
    }
  }
}

template <int P>
__global__ __launch_bounds__(512, 1) void layer_kernel(
    const float* __restrict__ W,
    const uint32_t* __restrict__ actIn,
    uint32_t* __restrict__ actOut) {
  __shared__ uint32_t shOut[BATCH];
  int tid = threadIdx.x;
  shOut[tid] = 0u;
  __syncthreads();

  int wave = tid >> 6;
  int lane = tid & 63;
  int hbase = blockIdx.x * 32;

  for (int r = 0; r < 4; ++r) {
    int h = hbase + wave * 4 + r;
    const float4* wrow = (const float4*)(W + (size_t)h * P) + lane;
    int z[8];
#pragma unroll
    for (int i = 0; i < 8; ++i) z[i] = 0;

#pragma unroll 4
    for (int it = 0; it < P / 256; ++it) {
      float4 wv = wrow[it * 64];
      int eb = it * 256;
      proc_comp<P>(wv.x, eb + 0, actIn, lane, z);
      proc_comp<P>(wv.y, eb + 1, actIn, lane, z);
      proc_comp<P>(wv.z, eb + 2, actIn, lane, z);
      proc_comp<P>(wv.w, eb + 3, actIn, lane, z);
    }

    uint32_t bitmask = 1u << (h & 31);
#pragma unroll
    for (int i = 0; i < 8; ++i) {
      if (z[i] >= THRESH_I) atomicOr(&shOut[i * 64 + lane], bitmask);
    }
  }
  __syncthreads();
  // block covers rows [32*bid, 32*bid+32) -> single word index = blockIdx.x
  actOut[(size_t)blockIdx.x * BATCH + tid] = shOut[tid];
}

// ---------------------------------------------------------------------------
// Output accumulation: outAcc[b][c] += sum over (layer,h) of bit * outConn.
// Grid: 8 batch-groups x 48 chunks of 512 rows (3*8192 total row space).
// ---------------------------------------------------------------------------
__global__ __launch_bounds__(256) void outacc_kernel(
    const float* __restrict__ outConn,
    const uint32_t* __restrict__ ab1,
    const uint32_t* __restrict__ ab2,
    const uint32_t* __restrict__ ab3,
    float* __restrict__ outAcc) {
  int bg = blockIdx.x & 7;
  int chunk = blockIdx.x >> 3;
  int wave = threadIdx.x >> 6;
  int lane = threadIdx.x & 63;
  int b = bg * 64 + lane;

  float acc[NCLS];
#pragma unroll
  for (int c = 0; c < NCLS; ++c) acc[c] = 0.0f;

  int gbase = chunk * 512 + wave * 128;
  for (int k = 0; k < 128; k += 32) {
    int g = gbase + k;                 // global row id in [0, 3*8192)
    int layer = g >> 13;
    int h = g & (HSIZE - 1);
    const uint32_t* ab = (layer == 0) ? ab1 : (layer == 1) ? ab2 : ab3;
    uint32_t wbits = ab[(size_t)(h >> 5) * BATCH + b];
#pragma unroll
    for (int j = 0; j < 32; ++j) {
      float bitf = (float)((wbits >> j) & 1u);
      const float* oc = outConn + (size_t)(g + j) * NCLS;
#pragma unroll
      for (int c = 0; c < NCLS; ++c) acc[c] += bitf * oc[c];
    }
  }
#pragma unroll
  for (int c = 0; c < NCLS; ++c) {
    atomicAdd(&outAcc[b * NCLS + c], acc[c]);
  }
}

// ---------------------------------------------------------------------------
// Final: argmax per batch; write preds (int32) then outAct (f32) into d_out.
// ---------------------------------------------------------------------------
__global__ __launch_bounds__(256) void final_kernel(
    const float* __restrict__ outAcc,
    int* __restrict__ preds,
    float* __restrict__ outF) {
  int b = blockIdx.x * 256 + threadIdx.x;
  if (b < BATCH) {
    float vals[NCLS];
#pragma unroll
    for (int c = 0; c < NCLS; ++c) vals[c] = outAcc[b * NCLS + c];
    float best = vals[0];
    int bi = 0;
#pragma unroll
    for (int c = 1; c < NCLS; ++c) {
      if (vals[c] > best) { best = vals[c]; bi = c; }
    }
    preds[b] = bi;
#pragma unroll
    for (int c = 0; c < NCLS; ++c) outF[b * NCLS + c] = vals[c];
  }
}

extern "C" void kernel_launch(void* const* d_in, const int* in_sizes, int n_in,
                              void* d_out, int out_size, void* d_ws, size_t ws_size,
                              hipStream_t stream) {
  const float* x       = (const float*)d_in[1];
  const float* W0      = (const float*)d_in[2];
  const float* W1      = (const float*)d_in[3];
  const float* W2      = (const float*)d_in[4];
  const float* outConn = (const float*)d_in[5];

  uint32_t* ws   = (uint32_t*)d_ws;
  uint32_t* act0 = ws;                          // 64*512  words (128 KB)
  uint32_t* act1 = act0 + EWORDS * BATCH;       // 256*512 words (512 KB)
  uint32_t* act2 = act1 + HWORDS * BATCH;
  uint32_t* act3 = act2 + HWORDS * BATCH;
  float* outAcc  = (float*)(act3 + HWORDS * BATCH);   // 512*10 f32

  encode_kernel<<<128, 256, 0, stream>>>(x, act0, outAcc);
  layer_kernel<2048><<<HSIZE / 32, 512, 0, stream>>>(W0, act0, act1);
  layer_kernel<8192><<<HSIZE / 32, 512, 0, stream>>>(W1, act1, act2);
  layer_kernel<8192><<<HSIZE / 32, 512, 0, stream>>>(W2, act2, act3);
  outacc_kernel<<<384, 256, 0, stream>>>(outConn, act1, act2, act3, outAcc);
  final_kernel<<<2, 256, 0, stream>>>(outAcc, (int*)d_out,
                                      (float*)d_out + BATCH);
}

// Round 2
// 760.408 us; speedup vs baseline: 1.1593x; 1.1593x over previous
//
#include <hip/hip_runtime.h>
#include <stdint.h>

#define BATCH   512
#define NFEAT   128
#define EWORDS  64     // E = 2048 bits -> 64 uint32 words
#define HSIZE   8192
#define HWORDS  256    // 8192 bits -> 256 uint32 words
#define NCLS    10
#define THRESH_I 4

// ---------------------------------------------------------------------------
// Encode: thermometer bits of x into bit matrix act0[word][batch].
// Word w holds features 2w (bits 0..15) and 2w+1 (bits 16..31).
// Also zeroes the outAcc accumulator (harness poisons ws with 0xAA).
// ---------------------------------------------------------------------------
__global__ __launch_bounds__(256) void encode_kernel(
    const float* __restrict__ x,
    uint32_t* __restrict__ act0,
    float* __restrict__ outAcc) {
  int t = blockIdx.x * 256 + threadIdx.x;        // 32768 threads
  if (t < BATCH * NCLS) outAcc[t] = 0.0f;
  int b = t >> 6;          // batch
  int w = t & 63;          // word index
  if (b < BATCH) {
    float u0 = x[b * NFEAT + 2 * w] * 16.0f;
    float u1 = x[b * NFEAT + 2 * w + 1] * 16.0f;
    uint32_t word = 0;
#pragma unroll
    for (int j = 0; j < 16; ++j) {
      word |= (u0 > (float)j ? 1u : 0u) << j;
      word |= (u1 > (float)j ? 1u : 0u) << (16 + j);
    }
    act0[w * BATCH + b] = word;
  }
}

// ---------------------------------------------------------------------------
// Layer: stream W rows; ballot finds nonzeros; per nonzero, lane loads the
// act bits of its 8 contiguous batches (2x uint4) and updates z counters.
// Block = 512 threads (8 waves), 2 rows/wave -> 16 rows/block -> one uint16
// half of the output word. Grid = 512 blocks (2 blocks/CU, 16 waves/CU).
// ---------------------------------------------------------------------------
__device__ __forceinline__ void proc_comp(float v, int ebase,
                                          const uint32_t* __restrict__ actIn,
                                          int lane, int* z) {
  uint64_t m = __ballot(v != 0.0f);
  if (m == 0ull) return;
  uint64_t pm = __ballot(v > 0.0f);
  do {
    uint32_t src = (uint32_t)__builtin_ctzll(m);
    m &= m - 1;
    int e = ebase + 4 * (int)src;                  // wave-uniform elem index
    const uint4* aw =
        (const uint4*)(actIn + (size_t)(e >> 5) * BATCH + lane * 8);
    uint4 a0 = aw[0];
    uint4 a1 = aw[1];
    uint32_t sh = (uint32_t)(e & 31);
    if ((pm >> src) & 1ull) {                      // wave-uniform branch
      z[0] += (int)((a0.x >> sh) & 1u);
      z[1] += (int)((a0.y >> sh) & 1u);
      z[2] += (int)((a0.z >> sh) & 1u);
      z[3] += (int)((a0.w >> sh) & 1u);
      z[4] += (int)((a1.x >> sh) & 1u);
      z[5] += (int)((a1.y >> sh) & 1u);
      z[6] += (int)((a1.z >> sh) & 1u);
      z[7] += (int)((a1.w >> sh) & 1u);
    } else {
      z[0] -= (int)((a0.x >> sh) & 1u);
      z[1] -= (int)((a0.y >> sh) & 1u);
      z[2] -= (int)((a0.z >> sh) & 1u);
      z[3] -= (int)((a0.w >> sh) & 1u);
      z[4] -= (int)((a1.x >> sh) & 1u);
      z[5] -= (int)((a1.y >> sh) & 1u);
      z[6] -= (int)((a1.z >> sh) & 1u);
      z[7] -= (int)((a1.w >> sh) & 1u);
    }
  } while (m);
}

__device__ __forceinline__ void proc_chunk(const float4* cur, int it,
                                           const uint32_t* __restrict__ actIn,
                                           int lane, int* z) {
#pragma unroll
  for (int k = 0; k < 4; ++k) {
    int eb = it * 1024 + k * 256;
    proc_comp(cur[k].x, eb + 0, actIn, lane, z);
    proc_comp(cur[k].y, eb + 1, actIn, lane, z);
    proc_comp(cur[k].z, eb + 2, actIn, lane, z);
    proc_comp(cur[k].w, eb + 3, actIn, lane, z);
  }
}

template <int P>
__global__ __launch_bounds__(512, 4) void layer_kernel(
    const float* __restrict__ W,
    const uint32_t* __restrict__ actIn,
    uint32_t* __restrict__ actOut) {
  __shared__ uint32_t shOut[BATCH];
  int tid = threadIdx.x;
  shOut[tid] = 0u;
  __syncthreads();

  int wave = tid >> 6;
  int lane = tid & 63;
  int hbase = blockIdx.x * 16;
  const float4* w4 = (const float4*)W;
  constexpr int NIT = P / 1024;                    // chunks of 1024 elems/wave

  for (int r = 0; r < 2; ++r) {
    int h = hbase + wave * 2 + r;
    size_t rowb = (size_t)h * (P / 4);
    int z[8];
#pragma unroll
    for (int i = 0; i < 8; ++i) z[i] = 0;

    float4 cur[4], nxt[4];
#pragma unroll
    for (int k = 0; k < 4; ++k) cur[k] = w4[rowb + k * 64 + lane];

    for (int it = 0; it < NIT - 1; ++it) {
#pragma unroll
      for (int k = 0; k < 4; ++k)
        nxt[k] = w4[rowb + (size_t)(it + 1) * 256 + k * 64 + lane];
      proc_chunk(cur, it, actIn, lane, z);
#pragma unroll
      for (int k = 0; k < 4; ++k) cur[k] = nxt[k];
    }
    proc_chunk(cur, NIT - 1, actIn, lane, z);

    uint32_t bitm = 1u << (h & 15);
#pragma unroll
    for (int i = 0; i < 8; ++i) {
      if (z[i] >= THRESH_I) atomicOr(&shOut[lane * 8 + i], bitm);
    }
  }
  __syncthreads();
  // block covers 16 rows = one uint16 half of word (blockIdx.x>>1)
  int word = (int)(blockIdx.x >> 1);
  int half = (int)(blockIdx.x & 1);
  ((uint16_t*)actOut)[(size_t)word * (BATCH * 2) + tid * 2 + half] =
      (uint16_t)shOut[tid];
}

// ---------------------------------------------------------------------------
// Output accumulation with LDS-staged outConn chunk (256 rows, padded to 12).
// Grid: 96 chunks x 8 batch-groups = 768 blocks of 256 threads.
// ---------------------------------------------------------------------------
#define CHUNK 256
__global__ __launch_bounds__(256, 4) void outacc_kernel(
    const float* __restrict__ outConn,
    const uint32_t* __restrict__ ab1,
    const uint32_t* __restrict__ ab2,
    const uint32_t* __restrict__ ab3,
    float* __restrict__ outAcc) {
  __shared__ float shOC[CHUNK][12];
  int tid = threadIdx.x;
  int bg = blockIdx.x & 7;
  int chunk = blockIdx.x >> 3;                     // 0..95
  int gbase = chunk * CHUNK;                       // global row base

  for (int idx = tid; idx < CHUNK * NCLS; idx += 256) {
    int r = idx / NCLS;
    int c = idx - r * NCLS;
    shOC[r][c] = outConn[(size_t)gbase * NCLS + idx];
  }
  __syncthreads();

  int wave = tid >> 6;
  int lane = tid & 63;
  int b = bg * 64 + lane;
  int layer = gbase >> 13;
  const uint32_t* ab = (layer == 0) ? ab1 : (layer == 1) ? ab2 : ab3;

  float acc[NCLS];
#pragma unroll
  for (int c = 0; c < NCLS; ++c) acc[c] = 0.0f;

  int rbase = wave * 64;                           // rows within chunk
  for (int k = 0; k < 2; ++k) {
    int rr = rbase + k * 32;
    int h = (gbase & (HSIZE - 1)) + rr;
    uint32_t wbits = ab[(size_t)(h >> 5) * BATCH + b];
    for (int j = 0; j < 32; ++j) {
      float bitf = (float)((wbits >> j) & 1u);
      const float* oc = shOC[rr + j];
#pragma unroll
      for (int c = 0; c < NCLS; ++c) acc[c] += bitf * oc[c];
    }
  }
#pragma unroll
  for (int c = 0; c < NCLS; ++c) {
    atomicAdd(&outAcc[b * NCLS + c], acc[c]);
  }
}

// ---------------------------------------------------------------------------
// Final: argmax per batch; write preds (int32) then outAct (f32) into d_out.
// ---------------------------------------------------------------------------
__global__ __launch_bounds__(256) void final_kernel(
    const float* __restrict__ outAcc,
    int* __restrict__ preds,
    float* __restrict__ outF) {
  int b = blockIdx.x * 256 + threadIdx.x;
  if (b < BATCH) {
    float vals[NCLS];
#pragma unroll
    for (int c = 0; c < NCLS; ++c) vals[c] = outAcc[b * NCLS + c];
    float best = vals[0];
    int bi = 0;
#pragma unroll
    for (int c = 1; c < NCLS; ++c) {
      if (vals[c] > best) { best = vals[c]; bi = c; }
    }
    preds[b] = bi;
#pragma unroll
    for (int c = 0; c < NCLS; ++c) outF[b * NCLS + c] = vals[c];
  }
}

extern "C" void kernel_launch(void* const* d_in, const int* in_sizes, int n_in,
                              void* d_out, int out_size, void* d_ws, size_t ws_size,
                              hipStream_t stream) {
  const float* x       = (const float*)d_in[1];
  const float* W0      = (const float*)d_in[2];
  const float* W1      = (const float*)d_in[3];
  const float* W2      = (const float*)d_in[4];
  const float* outConn = (const float*)d_in[5];

  uint32_t* ws   = (uint32_t*)d_ws;
  uint32_t* act0 = ws;                          // 64*512  words (128 KB)
  uint32_t* act1 = act0 + EWORDS * BATCH;       // 256*512 words (512 KB)
  uint32_t* act2 = act1 + HWORDS * BATCH;
  uint32_t* act3 = act2 + HWORDS * BATCH;
  float* outAcc  = (float*)(act3 + HWORDS * BATCH);   // 512*10 f32

  encode_kernel<<<128, 256, 0, stream>>>(x, act0, outAcc);
  layer_kernel<2048><<<HSIZE / 16, 512, 0, stream>>>(W0, act0, act1);
  layer_kernel<8192><<<HSIZE / 16, 512, 0, stream>>>(W1, act1, act2);
  layer_kernel<8192><<<HSIZE / 16, 512, 0, stream>>>(W2, act2, act3);
  outacc_kernel<<<768, 256, 0, stream>>>(outConn, act1, act2, act3, outAcc);
  final_kernel<<<2, 256, 0, stream>>>(outAcc, (int*)d_out,
                                      (float*)d_out + BATCH);
}